// Round 1
// 103.519 us; speedup vs baseline: 1.0353x; 1.0353x over previous
//
#include <hip/hip_runtime.h>
#include <hip/hip_bf16.h>
#include <cstdint>

// adknnLoss: N=8192, M=128.
//   A = L*X; B = (X@Wnet + bnet)*X
//   dist[i,j] = ||A_i - B_j||; drum = exp(-dist)
//   pred = (drum@Y)/drum.sum(1); loss = sum((Y-pred)^2)
//
// Round 4: pairwise B-reuse doubled (rt=4 -> 64 rows/wave), halving L2 read
// traffic 512MB -> 256MB (was the binding ceiling at ~15us > trans-pipe 11us).
// Grid (32,16), __launch_bounds__(256,2) for ~175 VGPR. finish widened to
// 8 blocks + atomicAdd(out) (out zeroed in prep).
//   w = exp(-dist) = 2^(-sqrt(K2*d2)),  K2 = (log2 e)^2, folded into norms.

#define N_ 8192
#define M_ 128
#define K2_ 2.0813689810056077f      // (log2 e)^2
#define NEG2K2_ -4.1627379620112154f // -2*(log2 e)^2

typedef __bf16 bf16x8 __attribute__((ext_vector_type(8)));
typedef float  f32x4  __attribute__((ext_vector_type(4)));

__device__ __forceinline__ unsigned short f2bf(float f) {
    unsigned int x = __float_as_uint(f);
    unsigned int r = x + 0x7fffu + ((x >> 16) & 1u);
    return (unsigned short)(r >> 16);
}

// Swizzled fragment layout (A and B operands of mfma_f32_16x16x32_bf16):
//   elem_off(row,k) = (row>>4)*2048 + (k>>5)*512 + ((k>>3)&3)*128 + (row&15)*8 + (k&7)
// Wave fragment load for (group g, ks): base + g*2048 + ks*512 + lane*8
// -> lane-contiguous 16 B/lane global_load_dwordx4.

// ---------------------------------------------------------------------------
// prep: Asw = swz(bf16(L*X)); Bsw = swz(bf16((X@Wnet+bnet)*X));
//       naS = K2*||a||^2; nbY = (K2*||b||^2, Y); zero sumw/sumwy/out.
// 512 blocks x 256 thr; 16 rows/block. Wnet staged in LDS (64 KB).
// thread = (rr,k4): rows rr*2, rr*2+1; out cols 4*k4..4*k4+3.
// ---------------------------------------------------------------------------
__global__ __launch_bounds__(256) void prep_kernel(
    const float* __restrict__ L, const float* __restrict__ X,
    const float* __restrict__ Y, const float* __restrict__ Wnet,
    const float* __restrict__ bnet,
    unsigned short* __restrict__ Asw, unsigned short* __restrict__ Bsw,
    float* __restrict__ naS, float2* __restrict__ nbY,
    float* __restrict__ sumw, float* __restrict__ sumwy,
    float* __restrict__ out)
{
    __shared__ float Ws[128 * 128];  // 64 KB
    __shared__ float Xs[16][128];    // 8 KB
    const int tid  = threadIdx.x;
    const int row0 = blockIdx.x * 16;
    const int k4   = tid & 31;
    const int rr   = tid >> 5;

    #pragma unroll
    for (int i = 0; i < 16; ++i)
        ((float4*)Ws)[tid + i * 256] = ((const float4*)Wnet)[tid + i * 256];
    #pragma unroll
    for (int i = 0; i < 2; ++i)
        ((float4*)Xs)[tid + i * 256] =
            ((const float4*)(X + (size_t)row0 * 128))[tid + i * 256];
    __syncthreads();

    float acc0[4] = {0.f, 0.f, 0.f, 0.f};
    float acc1[4] = {0.f, 0.f, 0.f, 0.f};
    const int r0 = rr * 2, r1 = rr * 2 + 1;
    #pragma unroll 2
    for (int c4 = 0; c4 < 128; c4 += 4) {
        const float4 x0 = *(const float4*)&Xs[r0][c4];
        const float4 x1 = *(const float4*)&Xs[r1][c4];
        const float4 wc0 = *(const float4*)&Ws[(c4 + 0) * 128 + k4 * 4];
        const float4 wc1 = *(const float4*)&Ws[(c4 + 1) * 128 + k4 * 4];
        const float4 wc2 = *(const float4*)&Ws[(c4 + 2) * 128 + k4 * 4];
        const float4 wc3 = *(const float4*)&Ws[(c4 + 3) * 128 + k4 * 4];
        const float x0e[4] = {x0.x, x0.y, x0.z, x0.w};
        const float x1e[4] = {x1.x, x1.y, x1.z, x1.w};
        const float4 wce[4] = {wc0, wc1, wc2, wc3};
        #pragma unroll
        for (int c = 0; c < 4; ++c) {
            acc0[0] = fmaf(x0e[c], wce[c].x, acc0[0]);
            acc0[1] = fmaf(x0e[c], wce[c].y, acc0[1]);
            acc0[2] = fmaf(x0e[c], wce[c].z, acc0[2]);
            acc0[3] = fmaf(x0e[c], wce[c].w, acc0[3]);
            acc1[0] = fmaf(x1e[c], wce[c].x, acc1[0]);
            acc1[1] = fmaf(x1e[c], wce[c].y, acc1[1]);
            acc1[2] = fmaf(x1e[c], wce[c].z, acc1[2]);
            acc1[3] = fmaf(x1e[c], wce[c].w, acc1[3]);
        }
    }

    const float4 bn4 = *(const float4*)(bnet + k4 * 4);
    float napart[2], nbpart[2];
    #pragma unroll
    for (int j = 0; j < 2; ++j) {
        const int ln  = rr * 2 + j;
        const int row = row0 + ln;
        const float* acc = j ? acc1 : acc0;
        const float4 xv = *(const float4*)(&Xs[ln][k4 * 4]);
        const float4 l4 = *(const float4*)(L + (size_t)row * 128 + k4 * 4);
        unsigned short apk[4], bpk[4];
        float nA_ = 0.f, nB_ = 0.f;
        const float xe[4] = {xv.x, xv.y, xv.z, xv.w};
        const float le[4] = {l4.x, l4.y, l4.z, l4.w};
        const float be[4] = {bn4.x, bn4.y, bn4.z, bn4.w};
        #pragma unroll
        for (int e = 0; e < 4; ++e) {
            float a = le[e] * xe[e];
            float b = (acc[e] + be[e]) * xe[e];
            unsigned short ua = f2bf(a), ub = f2bf(b);
            apk[e] = ua; bpk[e] = ub;
            float af = __uint_as_float((unsigned)ua << 16);
            float bf = __uint_as_float((unsigned)ub << 16);
            nA_ = fmaf(af, af, nA_);
            nB_ = fmaf(bf, bf, nB_);
        }
        napart[j] = nA_; nbpart[j] = nB_;
        size_t off = (size_t)blockIdx.x * 2048 + (size_t)(k4 >> 3) * 512
                   + (size_t)((k4 >> 1) & 3) * 128 + (size_t)ln * 8 + (k4 & 1) * 4;
        uint2 pa = make_uint2((unsigned)apk[0] | ((unsigned)apk[1] << 16),
                              (unsigned)apk[2] | ((unsigned)apk[3] << 16));
        uint2 pb = make_uint2((unsigned)bpk[0] | ((unsigned)bpk[1] << 16),
                              (unsigned)bpk[2] | ((unsigned)bpk[3] << 16));
        *(uint2*)(Asw + off) = pa;
        *(uint2*)(Bsw + off) = pb;
    }

    #pragma unroll
    for (int m = 1; m <= 16; m <<= 1) {
        napart[0] += __shfl_xor(napart[0], m, 64);
        napart[1] += __shfl_xor(napart[1], m, 64);
        nbpart[0] += __shfl_xor(nbpart[0], m, 64);
        nbpart[1] += __shfl_xor(nbpart[1], m, 64);
    }
    if (k4 == 0) {
        #pragma unroll
        for (int j = 0; j < 2; ++j) {
            int row = row0 + rr * 2 + j;
            naS[row] = K2_ * napart[j];
            nbY[row] = make_float2(K2_ * nbpart[j], Y[row]);
        }
    }
    if (tid < 16) sumw[row0 + tid] = 0.f;
    else if (tid < 32) sumwy[row0 + tid - 16] = 0.f;
    if (blockIdx.x == 0 && tid == 32) out[0] = 0.f;
}

// ---------------------------------------------------------------------------
// pairwise: grid (32, 16), 256 thr (4 waves). i-tile 256 rows (64/wave = rt 0..3),
// j-chunk 512 cols = 32 groups of 16. NO LDS, no barriers: B fragments are
// lane-contiguous global_load_dwordx4 from the L2-resident swizzled Bsw;
// waves run fully independently. rt=4 halves total B-side L2 traffic vs rt=2.
// ---------------------------------------------------------------------------
__global__ __launch_bounds__(256, 2) void pairwise_kernel(
    const unsigned short* __restrict__ Asw, const unsigned short* __restrict__ Bsw,
    const float* __restrict__ naS, const float2* __restrict__ nbY,
    float* __restrict__ sumw, float* __restrict__ sumwy)
{
    const int tid  = threadIdx.x;
    const int wv   = tid >> 6;
    const int lane = tid & 63;
    const int ln16 = lane & 15;
    const int quad = lane >> 4;
    const int i0   = blockIdx.x * 256;
    const int j0   = blockIdx.y * 512;

    // persistent A fragments + scaled norms (64 rows per wave)
    bf16x8 afrag[4][4];
    float  na[4][4];
    #pragma unroll
    for (int rt = 0; rt < 4; ++rt) {
        const int gA = (i0 >> 4) + wv * 4 + rt;
        const unsigned short* ap = Asw + (size_t)gA * 2048 + lane * 8;
        #pragma unroll
        for (int ks = 0; ks < 4; ++ks)
            afrag[rt][ks] = *(const bf16x8*)(ap + ks * 512);
        #pragma unroll
        for (int r = 0; r < 4; ++r)
            na[rt][r] = naS[gA * 16 + quad * 4 + r];
    }

    float accw[4][4], accwy[4][4];
    #pragma unroll
    for (int rt = 0; rt < 4; ++rt)
        #pragma unroll
        for (int r = 0; r < 4; ++r) { accw[rt][r] = 0.f; accwy[rt][r] = 0.f; }

    const unsigned short* bbase = Bsw + (size_t)(j0 >> 4) * 2048 + lane * 8;
    const float2* nbbase = nbY + j0 + ln16;

    #pragma unroll 2
    for (int ct = 0; ct < 32; ++ct) {
        const unsigned short* bp = bbase + (size_t)ct * 2048;
        bf16x8 bfrag[4];
        #pragma unroll
        for (int ks = 0; ks < 4; ++ks)
            bfrag[ks] = *(const bf16x8*)(bp + ks * 512);
        const float2 nv = nbbase[ct * 16];

        #pragma unroll
        for (int rt = 0; rt < 4; ++rt) {
            f32x4 s = {0.f, 0.f, 0.f, 0.f};
            #pragma unroll
            for (int ks = 0; ks < 4; ++ks)
                s = __builtin_amdgcn_mfma_f32_16x16x32_bf16(
                        afrag[rt][ks], bfrag[ks], s, 0, 0, 0);
            #pragma unroll
            for (int r = 0; r < 4; ++r) {
                float d2 = fmaf(NEG2K2_, s[r], na[rt][r] + nv.x);
                d2 = fmaxf(d2, 0.f);
                float w = __builtin_amdgcn_exp2f(-__builtin_amdgcn_sqrtf(d2));
                accw[rt][r] += w;
                accwy[rt][r] = fmaf(w, nv.y, accwy[rt][r]);
            }
        }
    }

    // reduce over the 16 column-lanes, one atomic per row
    #pragma unroll
    for (int rt = 0; rt < 4; ++rt)
        #pragma unroll
        for (int r = 0; r < 4; ++r) {
            float w  = accw[rt][r];
            float wy = accwy[rt][r];
            #pragma unroll
            for (int m = 1; m <= 8; m <<= 1) {
                w  += __shfl_xor(w,  m, 64);
                wy += __shfl_xor(wy, m, 64);
            }
            if (ln16 == 0) {
                int row = i0 + wv * 64 + rt * 16 + quad * 4 + r;
                atomicAdd(&sumw[row],  w);
                atomicAdd(&sumwy[row], wy);
            }
        }
}

// ---------------------------------------------------------------------------
// finish: 8 blocks x 256 thr; each thread handles 4 rows (float4).
// Partial loss per block -> atomicAdd into out (zeroed by prep).
// ---------------------------------------------------------------------------
__global__ __launch_bounds__(256) void finish_kernel(
    const float* __restrict__ Y, const float* __restrict__ sumw,
    const float* __restrict__ sumwy, float* __restrict__ out)
{
    __shared__ float red[4];
    const int tid = threadIdx.x;
    const int idx = blockIdx.x * 256 + tid;
    float4 w4  = ((const float4*)sumw)[idx];
    float4 wy4 = ((const float4*)sumwy)[idx];
    float4 y4  = ((const float4*)Y)[idx];
    const float we[4]  = {w4.x, w4.y, w4.z, w4.w};
    const float wye[4] = {wy4.x, wy4.y, wy4.z, wy4.w};
    const float ye[4]  = {y4.x, y4.y, y4.z, y4.w};
    float acc = 0.f;
    #pragma unroll
    for (int e = 0; e < 4; ++e) {
        float pred = wye[e] * __builtin_amdgcn_rcpf(we[e]);
        float d = ye[e] - pred;
        acc = fmaf(d, d, acc);
    }
    #pragma unroll
    for (int m = 1; m < 64; m <<= 1) acc += __shfl_xor(acc, m, 64);
    if ((tid & 63) == 0) red[tid >> 6] = acc;
    __syncthreads();
    if (tid == 0) {
        float v = red[0] + red[1] + red[2] + red[3];
        atomicAdd(out, v);
    }
}

// ---------------------------------------------------------------------------
extern "C" void kernel_launch(void* const* d_in, const int* in_sizes, int n_in,
                              void* d_out, int out_size, void* d_ws, size_t ws_size,
                              hipStream_t stream)
{
    const float* L    = (const float*)d_in[0];
    const float* X    = (const float*)d_in[1];
    const float* Y    = (const float*)d_in[2];
    const float* Wnet = (const float*)d_in[3];
    const float* bnet = (const float*)d_in[4];
    float* out = (float*)d_out;

    // ws: Asw 2MB | Bsw 2MB | naS 32KB | nbY 64KB | sumw 32KB | sumwy 32KB
    char* ws = (char*)d_ws;
    unsigned short* Asw = (unsigned short*)(ws);
    unsigned short* Bsw = (unsigned short*)(ws + (size_t)2 * 1024 * 1024);
    float*  naS   = (float*) (ws + (size_t)4 * 1024 * 1024);
    float2* nbYp  = (float2*)(ws + (size_t)4 * 1024 * 1024 + 32 * 1024);
    float*  sumw  = (float*) (ws + (size_t)4 * 1024 * 1024 + 96 * 1024);
    float*  sumwy = (float*) (ws + (size_t)4 * 1024 * 1024 + 128 * 1024);

    prep_kernel<<<N_ / 16, 256, 0, stream>>>(L, X, Y, Wnet, bnet,
                                             Asw, Bsw, naS, nbYp, sumw, sumwy, out);
    pairwise_kernel<<<dim3(N_ / 256, 16), 256, 0, stream>>>(Asw, Bsw, naS, nbYp,
                                                            sumw, sumwy);
    finish_kernel<<<8, 256, 0, stream>>>(Y, sumw, sumwy, out);
}

// Round 3
// 102.828 us; speedup vs baseline: 1.0422x; 1.0067x over previous
//
#include <hip/hip_runtime.h>
#include <hip/hip_bf16.h>
#include <cstdint>

// adknnLoss: N=8192, M=128.
//   A = L*X; B = (X@Wnet + bnet)*X
//   dist[i,j] = ||A_i - B_j||; drum = exp(-dist)
//   pred = (drum@Y)/drum.sum(1); loss = sum((Y-pred)^2)
//
// Round 6: revert to 3-kernel structure (R5's cooperative fused launch was
// rejected by the runtime -> silent no-launch). Keep R5's math folding:
// operands pre-scaled by sqrt(2*K2), norms stored negated-halved, norm terms
// folded into the MFMA C-operand init, so s = a~.b~ + Cinit = -K2*d2 and
//   w = exp2(-sqrt(abs(s)))    (abs/neg are free input modifiers)
// -> pairwise epilogue: 3 VALU + 2 trans per pair (was 5 VALU + 2 trans).

#define N_ 8192
#define M_ 128
#define SQRT2K2_ 2.0402789f  // sqrt(2*(log2 e)^2); dot of scaled ops = 2*K2*(a.b)

typedef __bf16 bf16x8 __attribute__((ext_vector_type(8)));
typedef float  f32x4  __attribute__((ext_vector_type(4)));

__device__ __forceinline__ unsigned short f2bf(float f) {
    unsigned int x = __float_as_uint(f);
    unsigned int r = x + 0x7fffu + ((x >> 16) & 1u);
    return (unsigned short)(r >> 16);
}

// Swizzled fragment layout (A and B operands of mfma_f32_16x16x32_bf16):
//   elem_off(row,k) = (row>>4)*2048 + (k>>5)*512 + ((k>>3)&3)*128 + (row&15)*8 + (k&7)
// Wave fragment load for (group g, ks): base + g*2048 + ks*512 + lane*8
// -> lane-contiguous 16 B/lane global_load_dwordx4.

// ---------------------------------------------------------------------------
// prep: Asw = swz(bf16(L*X*s)); Bsw = swz(bf16((X@Wnet+bnet)*X*s)), s=sqrt(2K2)
//       naS = -0.5*||a~||^2; nbY = (-0.5*||b~||^2, Y); zero sumw/sumwy/out.
// 512 blocks x 256 thr; 16 rows/block. Wnet staged in LDS (64 KB).
// thread = (rr,k4): rows rr*2, rr*2+1; out cols 4*k4..4*k4+3.
// ---------------------------------------------------------------------------
__global__ __launch_bounds__(256) void prep_kernel(
    const float* __restrict__ L, const float* __restrict__ X,
    const float* __restrict__ Y, const float* __restrict__ Wnet,
    const float* __restrict__ bnet,
    unsigned short* __restrict__ Asw, unsigned short* __restrict__ Bsw,
    float* __restrict__ naS, float2* __restrict__ nbY,
    float* __restrict__ sumw, float* __restrict__ sumwy,
    float* __restrict__ out)
{
    __shared__ float Ws[128 * 128];  // 64 KB
    __shared__ float Xs[16][128];    // 8 KB
    const int tid  = threadIdx.x;
    const int row0 = blockIdx.x * 16;
    const int k4   = tid & 31;
    const int rr   = tid >> 5;

    #pragma unroll
    for (int i = 0; i < 16; ++i)
        ((float4*)Ws)[tid + i * 256] = ((const float4*)Wnet)[tid + i * 256];
    #pragma unroll
    for (int i = 0; i < 2; ++i)
        ((float4*)Xs)[tid + i * 256] =
            ((const float4*)(X + (size_t)row0 * 128))[tid + i * 256];
    __syncthreads();

    float acc0[4] = {0.f, 0.f, 0.f, 0.f};
    float acc1[4] = {0.f, 0.f, 0.f, 0.f};
    const int r0 = rr * 2, r1 = rr * 2 + 1;
    #pragma unroll 2
    for (int c4 = 0; c4 < 128; c4 += 4) {
        const float4 x0 = *(const float4*)&Xs[r0][c4];
        const float4 x1 = *(const float4*)&Xs[r1][c4];
        const float4 wc0 = *(const float4*)&Ws[(c4 + 0) * 128 + k4 * 4];
        const float4 wc1 = *(const float4*)&Ws[(c4 + 1) * 128 + k4 * 4];
        const float4 wc2 = *(const float4*)&Ws[(c4 + 2) * 128 + k4 * 4];
        const float4 wc3 = *(const float4*)&Ws[(c4 + 3) * 128 + k4 * 4];
        const float x0e[4] = {x0.x, x0.y, x0.z, x0.w};
        const float x1e[4] = {x1.x, x1.y, x1.z, x1.w};
        const float4 wce[4] = {wc0, wc1, wc2, wc3};
        #pragma unroll
        for (int c = 0; c < 4; ++c) {
            acc0[0] = fmaf(x0e[c], wce[c].x, acc0[0]);
            acc0[1] = fmaf(x0e[c], wce[c].y, acc0[1]);
            acc0[2] = fmaf(x0e[c], wce[c].z, acc0[2]);
            acc0[3] = fmaf(x0e[c], wce[c].w, acc0[3]);
            acc1[0] = fmaf(x1e[c], wce[c].x, acc1[0]);
            acc1[1] = fmaf(x1e[c], wce[c].y, acc1[1]);
            acc1[2] = fmaf(x1e[c], wce[c].z, acc1[2]);
            acc1[3] = fmaf(x1e[c], wce[c].w, acc1[3]);
        }
    }

    const float4 bn4 = *(const float4*)(bnet + k4 * 4);
    float napart[2], nbpart[2];
    #pragma unroll
    for (int j = 0; j < 2; ++j) {
        const int ln  = rr * 2 + j;
        const int row = row0 + ln;
        const float* acc = j ? acc1 : acc0;
        const float4 xv = *(const float4*)(&Xs[ln][k4 * 4]);
        const float4 l4 = *(const float4*)(L + (size_t)row * 128 + k4 * 4);
        unsigned short apk[4], bpk[4];
        float nA_ = 0.f, nB_ = 0.f;
        const float xe[4] = {xv.x, xv.y, xv.z, xv.w};
        const float le[4] = {l4.x, l4.y, l4.z, l4.w};
        const float be[4] = {bn4.x, bn4.y, bn4.z, bn4.w};
        #pragma unroll
        for (int e = 0; e < 4; ++e) {
            float a = le[e] * xe[e] * SQRT2K2_;
            float b = (acc[e] + be[e]) * xe[e] * SQRT2K2_;
            unsigned short ua = f2bf(a), ub = f2bf(b);
            apk[e] = ua; bpk[e] = ub;
            float af = __uint_as_float((unsigned)ua << 16);
            float bf = __uint_as_float((unsigned)ub << 16);
            nA_ = fmaf(af, af, nA_);
            nB_ = fmaf(bf, bf, nB_);
        }
        napart[j] = nA_; nbpart[j] = nB_;
        size_t off = (size_t)blockIdx.x * 2048 + (size_t)(k4 >> 3) * 512
                   + (size_t)((k4 >> 1) & 3) * 128 + (size_t)ln * 8 + (k4 & 1) * 4;
        uint2 pa = make_uint2((unsigned)apk[0] | ((unsigned)apk[1] << 16),
                              (unsigned)apk[2] | ((unsigned)apk[3] << 16));
        uint2 pb = make_uint2((unsigned)bpk[0] | ((unsigned)bpk[1] << 16),
                              (unsigned)bpk[2] | ((unsigned)bpk[3] << 16));
        *(uint2*)(Asw + off) = pa;
        *(uint2*)(Bsw + off) = pb;
    }

    #pragma unroll
    for (int m = 1; m <= 16; m <<= 1) {
        napart[0] += __shfl_xor(napart[0], m, 64);
        napart[1] += __shfl_xor(napart[1], m, 64);
        nbpart[0] += __shfl_xor(nbpart[0], m, 64);
        nbpart[1] += __shfl_xor(nbpart[1], m, 64);
    }
    if (k4 == 0) {
        #pragma unroll
        for (int j = 0; j < 2; ++j) {
            int row = row0 + rr * 2 + j;
            naS[row] = -0.5f * napart[j];
            nbY[row] = make_float2(-0.5f * nbpart[j], Y[row]);
        }
    }
    if (tid < 16) sumw[row0 + tid] = 0.f;
    else if (tid < 32) sumwy[row0 + tid - 16] = 0.f;
    if (blockIdx.x == 0 && tid == 32) out[0] = 0.f;
}

// ---------------------------------------------------------------------------
// pairwise: grid (32, 16), 256 thr (4 waves). i-tile 256 rows (64/wave = rt 0..3),
// j-chunk 512 cols = 32 groups of 16. NO LDS, no barriers: B fragments are
// lane-contiguous global_load_dwordx4 from the L2-resident swizzled Bsw;
// waves run fully independently. Norm terms pre-folded into MFMA C-init.
// ---------------------------------------------------------------------------
__global__ __launch_bounds__(256, 2) void pairwise_kernel(
    const unsigned short* __restrict__ Asw, const unsigned short* __restrict__ Bsw,
    const float* __restrict__ naS, const float2* __restrict__ nbY,
    float* __restrict__ sumw, float* __restrict__ sumwy)
{
    const int tid  = threadIdx.x;
    const int wv   = tid >> 6;
    const int lane = tid & 63;
    const int ln16 = lane & 15;
    const int quad = lane >> 4;
    const int i0   = blockIdx.x * 256;
    const int j0   = blockIdx.y * 512;

    // persistent A fragments + negated half-norms (64 rows per wave)
    bf16x8 afrag[4][4];
    float  nna[4][4];
    #pragma unroll
    for (int rt = 0; rt < 4; ++rt) {
        const int gA = (i0 >> 4) + wv * 4 + rt;
        const unsigned short* ap = Asw + (size_t)gA * 2048 + lane * 8;
        #pragma unroll
        for (int ks = 0; ks < 4; ++ks)
            afrag[rt][ks] = *(const bf16x8*)(ap + ks * 512);
        #pragma unroll
        for (int r = 0; r < 4; ++r)
            nna[rt][r] = naS[gA * 16 + quad * 4 + r];
    }

    float accw[4][4], accwy[4][4];
    #pragma unroll
    for (int rt = 0; rt < 4; ++rt)
        #pragma unroll
        for (int r = 0; r < 4; ++r) { accw[rt][r] = 0.f; accwy[rt][r] = 0.f; }

    const unsigned short* bbase = Bsw + (size_t)(j0 >> 4) * 2048 + lane * 8;
    const float2* nbbase = nbY + j0 + ln16;

    #pragma unroll 2
    for (int ct = 0; ct < 32; ++ct) {
        const unsigned short* bp = bbase + (size_t)ct * 2048;
        bf16x8 bfrag[4];
        #pragma unroll
        for (int ks = 0; ks < 4; ++ks)
            bfrag[ks] = *(const bf16x8*)(bp + ks * 512);
        const float2 nv = nbbase[ct * 16];

        #pragma unroll
        for (int rt = 0; rt < 4; ++rt) {
            f32x4 s;
            #pragma unroll
            for (int r = 0; r < 4; ++r) s[r] = nna[rt][r] + nv.x;
            #pragma unroll
            for (int ks = 0; ks < 4; ++ks)
                s = __builtin_amdgcn_mfma_f32_16x16x32_bf16(
                        afrag[rt][ks], bfrag[ks], s, 0, 0, 0);
            // s = a~.b~ - 0.5||a~||^2 - 0.5||b~||^2 = -K2*d2
            #pragma unroll
            for (int r = 0; r < 4; ++r) {
                float w = __builtin_amdgcn_exp2f(
                              -__builtin_amdgcn_sqrtf(__builtin_fabsf(s[r])));
                accw[rt][r] += w;
                accwy[rt][r] = fmaf(w, nv.y, accwy[rt][r]);
            }
        }
    }

    // reduce over the 16 column-lanes, one atomic per row
    #pragma unroll
    for (int rt = 0; rt < 4; ++rt)
        #pragma unroll
        for (int r = 0; r < 4; ++r) {
            float w  = accw[rt][r];
            float wy = accwy[rt][r];
            #pragma unroll
            for (int m = 1; m <= 8; m <<= 1) {
                w  += __shfl_xor(w,  m, 64);
                wy += __shfl_xor(wy, m, 64);
            }
            if (ln16 == 0) {
                int row = i0 + wv * 64 + rt * 16 + quad * 4 + r;
                atomicAdd(&sumw[row],  w);
                atomicAdd(&sumwy[row], wy);
            }
        }
}

// ---------------------------------------------------------------------------
// finish: 8 blocks x 256 thr; each thread handles 4 rows (float4).
// Partial loss per block -> atomicAdd into out (zeroed by prep).
// ---------------------------------------------------------------------------
__global__ __launch_bounds__(256) void finish_kernel(
    const float* __restrict__ Y, const float* __restrict__ sumw,
    const float* __restrict__ sumwy, float* __restrict__ out)
{
    __shared__ float red[4];
    const int tid = threadIdx.x;
    const int idx = blockIdx.x * 256 + tid;
    float4 w4  = ((const float4*)sumw)[idx];
    float4 wy4 = ((const float4*)sumwy)[idx];
    float4 y4  = ((const float4*)Y)[idx];
    const float we[4]  = {w4.x, w4.y, w4.z, w4.w};
    const float wye[4] = {wy4.x, wy4.y, wy4.z, wy4.w};
    const float ye[4]  = {y4.x, y4.y, y4.z, y4.w};
    float acc = 0.f;
    #pragma unroll
    for (int e = 0; e < 4; ++e) {
        float pred = wye[e] * __builtin_amdgcn_rcpf(we[e]);
        float d = ye[e] - pred;
        acc = fmaf(d, d, acc);
    }
    #pragma unroll
    for (int m = 1; m < 64; m <<= 1) acc += __shfl_xor(acc, m, 64);
    if ((tid & 63) == 0) red[tid >> 6] = acc;
    __syncthreads();
    if (tid == 0) {
        float v = red[0] + red[1] + red[2] + red[3];
        atomicAdd(out, v);
    }
}

// ---------------------------------------------------------------------------
extern "C" void kernel_launch(void* const* d_in, const int* in_sizes, int n_in,
                              void* d_out, int out_size, void* d_ws, size_t ws_size,
                              hipStream_t stream)
{
    const float* L    = (const float*)d_in[0];
    const float* X    = (const float*)d_in[1];
    const float* Y    = (const float*)d_in[2];
    const float* Wnet = (const float*)d_in[3];
    const float* bnet = (const float*)d_in[4];
    float* out = (float*)d_out;

    // ws: Asw 2MB | Bsw 2MB | naS 32KB | nbY 64KB | sumw 32KB | sumwy 32KB
    char* ws = (char*)d_ws;
    unsigned short* Asw = (unsigned short*)(ws);
    unsigned short* Bsw = (unsigned short*)(ws + (size_t)2 * 1024 * 1024);
    float*  naS   = (float*) (ws + (size_t)4 * 1024 * 1024);
    float2* nbYp  = (float2*)(ws + (size_t)4 * 1024 * 1024 + 32 * 1024);
    float*  sumw  = (float*) (ws + (size_t)4 * 1024 * 1024 + 96 * 1024);
    float*  sumwy = (float*) (ws + (size_t)4 * 1024 * 1024 + 128 * 1024);

    prep_kernel<<<N_ / 16, 256, 0, stream>>>(L, X, Y, Wnet, bnet,
                                             Asw, Bsw, naS, nbYp, sumw, sumwy, out);
    pairwise_kernel<<<dim3(N_ / 256, 16), 256, 0, stream>>>(Asw, Bsw, naS, nbYp,
                                                            sumw, sumwy);
    finish_kernel<<<8, 256, 0, stream>>>(Y, sumw, sumwy, out);
}